// Round 2
// baseline (211.501 us; speedup 1.0000x reference)
//
#include <hip/hip_runtime.h>
#include <stdint.h>

typedef __attribute__((ext_vector_type(8))) short bf16x8;
typedef __attribute__((ext_vector_type(4))) float f32x4;

// LDS map (bytes):
//   [0, 90112)      weight fragments, bf16, MFMA-B order: frag f, lane ln, elem j
//                   at short index f*512 + ln*8 + j
//     QKV: frags 0..23   (12 n-tiles x 2 k-halves; n-tile nt = sel*4 + head)
//     W1 : frags @24576B (16 n-tiles x 2 k-halves)
//     W2 : frags @57344B (8 k-slices x 4 n-tiles, f = ksl*4 + nt)
//   [90112, 160768) 8 per-wave arenas of 8832 B:
//     +0    qS [16][68] bf16      (overlaid by sl0/sl1 during MLP)
//     +2176 kS [16][68]
//     +4352 vS [16][68]
//     +6528 hS [16][72]  (h / attn-concat / sa / h2 / ff bounce buffer)

static __device__ __forceinline__ unsigned short f2bf(float f) {
    unsigned int u = __float_as_uint(f);
    return (unsigned short)((u + 0x7FFFu + ((u >> 16) & 1u)) >> 16);
}
static __device__ __forceinline__ float bf2f(unsigned int b) {
    return __uint_as_float(b << 16);
}

__global__ __launch_bounds__(512, 2)
void fused_block(const float* __restrict__ xg,
                 const float* __restrict__ Wq, const float* __restrict__ Wk,
                 const float* __restrict__ Wv, const float* __restrict__ Wp,
                 const float* __restrict__ bp, const float* __restrict__ W1,
                 const float* __restrict__ b1, const float* __restrict__ W2,
                 const float* __restrict__ b2, const float* __restrict__ g1,
                 const float* __restrict__ be1, const float* __restrict__ g2,
                 const float* __restrict__ be2, float* __restrict__ out,
                 int nPairsTotal)
{
    __shared__ __align__(16) unsigned char LDS[160768];

    const int tid  = threadIdx.x;
    const int lane = tid & 63;
    const int wid  = tid >> 6;
    const int fr   = lane & 15;       // MFMA fragment row/col index
    const int fg   = lane >> 4;       // MFMA fragment k-group
    const int xr   = lane >> 2;       // x row owned by this lane (0..15)
    const int xc   = (lane & 3) * 16; // x col base (0,16,32,48)

    // ---------------- weight preload into LDS (bf16 fragments) ----------------
    {
        unsigned short* lw = (unsigned short*)LDS;
        #pragma unroll 1
        for (int e = tid; e < 45056; e += 512) {
            int j  = e & 7;
            int ln = (e >> 3) & 63;
            float src;
            if (e < 12288) {                       // QKV: [64 x 192], col = 16*(sel*4+h)+d
                int ks = (e >> 9) & 1, nt = e >> 10;
                int k = 8*(ln>>4) + j + 32*ks;
                int d = ln & 15, h = nt & 3, sel = nt >> 2;
                const float* W = (sel == 0) ? Wq : ((sel == 1) ? Wk : Wv);
                src = W[h*1024 + k*16 + d];
            } else if (e < 28672) {                // W1 [64 x 256]
                int t = e - 12288;
                int ks = (t >> 9) & 1, nt = t >> 10;
                int k = 8*(ln>>4) + j + 32*ks;
                src = W1[k*256 + 16*nt + (ln & 15)];
            } else {                               // W2 [256 x 64]
                int t = e - 28672;
                int nt = (t >> 9) & 3, ksl = t >> 11;
                int k = 32*ksl + 8*(ln>>4) + j;
                src = W2[k*64 + 16*nt + (ln & 15)];
            }
            lw[e] = f2bf(src);
        }
    }

    // Wp fragments in registers
    bf16x8 wpf[4][2];
    #pragma unroll
    for (int nt = 0; nt < 4; ++nt)
        #pragma unroll
        for (int ks = 0; ks < 2; ++ks) {
            bf16x8 v;
            #pragma unroll
            for (int j = 0; j < 8; ++j)
                v[j] = (short)f2bf(Wp[(8*fg + j + 32*ks)*64 + 16*nt + fr]);
            wpf[nt][ks] = v;
        }

    // per-lane parameters
    float g1v[16], be1v[16], g2v[16], be2v[16];
    #pragma unroll
    for (int j = 0; j < 16; ++j) {
        int c = xc + j;
        g1v[j] = g1[c]; be1v[j] = be1[c]; g2v[j] = g2[c]; be2v[j] = be2[c];
    }
    float b1v[16], bpv[4], b2v[4];
    #pragma unroll
    for (int nt = 0; nt < 16; ++nt) b1v[nt] = b1[16*nt + fr];
    #pragma unroll
    for (int nt = 0; nt < 4; ++nt) { bpv[nt] = bp[16*nt + fr]; b2v[nt] = b2[16*nt + fr]; }

    __syncthreads();

    unsigned char* arena = LDS + 90112 + wid * 8832;
    unsigned short* qS  = (unsigned short*)(arena);
    unsigned short* kS  = (unsigned short*)(arena + 2176);
    unsigned short* vS  = (unsigned short*)(arena + 4352);
    unsigned short* hS  = (unsigned short*)(arena + 6528);
    unsigned short* sl0 = (unsigned short*)(arena);
    unsigned short* sl1 = (unsigned short*)(arena + 1280);

    const int pipe  = blockIdx.x * 8 + wid;
    const int iters = nPairsTotal >> 11;   // nPairsTotal divisible by 2048 (32768/2048=16)

    #pragma unroll 1
    for (int it = 0; it < iters; ++it) {
        const int gp = pipe + (it << 11);
        const float* xb = xg + (size_t)gp * 1024;
        float*       ob = out + (size_t)gp * 1024;

        // x: lane owns row xr, cols xc..xc+15
        f32x4 xv[4];
        #pragma unroll
        for (int i = 0; i < 4; ++i)
            xv[i] = *(const f32x4*)(xb + xr*64 + xc + 4*i);

        // ---- LN1 -> h (bf16) -> hS ----
        {
            float s = 0.f, ss = 0.f;
            #pragma unroll
            for (int i = 0; i < 4; ++i)
                #pragma unroll
                for (int j = 0; j < 4; ++j) { float v = xv[i][j]; s += v; ss += v*v; }
            s += __shfl_xor(s, 1, 64); ss += __shfl_xor(ss, 1, 64);
            s += __shfl_xor(s, 2, 64); ss += __shfl_xor(ss, 2, 64);
            float mu  = s * 0.015625f;
            float inv = rsqrtf(ss * 0.015625f - mu*mu + 1e-5f);
            #pragma unroll
            for (int i = 0; i < 4; ++i) {
                uint2 w;
                w.x = (unsigned)f2bf((xv[i][0]-mu)*inv*g1v[4*i+0] + be1v[4*i+0])
                    | ((unsigned)f2bf((xv[i][1]-mu)*inv*g1v[4*i+1] + be1v[4*i+1]) << 16);
                w.y = (unsigned)f2bf((xv[i][2]-mu)*inv*g1v[4*i+2] + be1v[4*i+2])
                    | ((unsigned)f2bf((xv[i][3]-mu)*inv*g1v[4*i+3] + be1v[4*i+3]) << 16);
                *((uint2*)(hS + xr*72 + xc + 4*i)) = w;
            }
        }
        __syncthreads();

        // ---- QKV = h @ [Wq|Wk|Wv] ----
        {
            bf16x8 a0 = *(const bf16x8*)(hS + fr*72 + 8*fg);
            bf16x8 a1 = *(const bf16x8*)(hS + fr*72 + 8*fg + 32);
            #pragma unroll
            for (int nt = 0; nt < 12; ++nt) {
                bf16x8 u0 = *(const bf16x8*)(LDS + (((nt*2+0)*64 + lane) << 4));
                bf16x8 u1 = *(const bf16x8*)(LDS + (((nt*2+1)*64 + lane) << 4));
                f32x4 acc = {0.f, 0.f, 0.f, 0.f};
                acc = __builtin_amdgcn_mfma_f32_16x16x32_bf16(a0, u0, acc, 0, 0, 0);
                acc = __builtin_amdgcn_mfma_f32_16x16x32_bf16(a1, u1, acc, 0, 0, 0);
                unsigned short* dst = (nt < 4) ? qS : ((nt < 8) ? kS : vS);
                int c = 16*(nt & 3) + fr;
                #pragma unroll
                for (int r = 0; r < 4; ++r)
                    dst[(4*fg + r)*68 + c] = f2bf(acc[r]);     // D: col=fr, row=4*fg+r
            }
        }
        __syncthreads();

        // ---- attention: lane = (pair-batch, head, tq) ----
        {
            int pb = lane >> 5, hd = (lane >> 3) & 3, tq = lane & 7;
            int qrow = 8*pb + tq;
            float qv[16];
            {
                const unsigned int* qp = (const unsigned int*)(qS + qrow*68 + 16*hd);
                #pragma unroll
                for (int u = 0; u < 8; ++u) {
                    unsigned int w = qp[u];
                    qv[2*u] = bf2f(w & 0xffffu); qv[2*u+1] = bf2f(w >> 16);
                }
            }
            float sc[8];
            #pragma unroll
            for (int tk = 0; tk < 8; ++tk) {
                const unsigned int* kp = (const unsigned int*)(kS + (8*pb + tk)*68 + 16*hd);
                float d = 0.f;
                #pragma unroll
                for (int u = 0; u < 8; ++u) {
                    unsigned int w = kp[u];
                    d += qv[2*u]*bf2f(w & 0xffffu) + qv[2*u+1]*bf2f(w >> 16);
                }
                sc[tk] = (tk <= tq) ? d * 0.125f : -1.0e30f;   // scale = C^-0.5 = 1/8
            }
            float mx = sc[0];
            #pragma unroll
            for (int tk = 1; tk < 8; ++tk) mx = fmaxf(mx, sc[tk]);
            float pw[8], ps = 0.f;
            #pragma unroll
            for (int tk = 0; tk < 8; ++tk) { pw[tk] = __expf(sc[tk] - mx); ps += pw[tk]; }
            float pinv = 1.f / ps;
            float av[16];
            #pragma unroll
            for (int j = 0; j < 16; ++j) av[j] = 0.f;
            #pragma unroll
            for (int tk = 0; tk < 8; ++tk) {
                float wgt = pw[tk];
                const unsigned int* vp = (const unsigned int*)(vS + (8*pb + tk)*68 + 16*hd);
                #pragma unroll
                for (int u = 0; u < 8; ++u) {
                    unsigned int w = vp[u];
                    av[2*u]   += wgt * bf2f(w & 0xffffu);
                    av[2*u+1] += wgt * bf2f(w >> 16);
                }
            }
            #pragma unroll
            for (int u = 0; u < 4; ++u) {
                uint2 w;
                w.x = (unsigned)f2bf(av[4*u+0]*pinv) | ((unsigned)f2bf(av[4*u+1]*pinv) << 16);
                w.y = (unsigned)f2bf(av[4*u+2]*pinv) | ((unsigned)f2bf(av[4*u+3]*pinv) << 16);
                *((uint2*)(hS + qrow*72 + 16*hd + 4*u)) = w;   // attn concat: col = 16*hd + d
            }
        }
        __syncthreads();

        // ---- proj: sa = attn @ Wp + bp ----
        f32x4 sacc[4];
        {
            bf16x8 p0 = *(const bf16x8*)(hS + fr*72 + 8*fg);
            bf16x8 p1 = *(const bf16x8*)(hS + fr*72 + 8*fg + 32);
            #pragma unroll
            for (int nt = 0; nt < 4; ++nt) {
                f32x4 acc = {0.f,0.f,0.f,0.f};
                acc = __builtin_amdgcn_mfma_f32_16x16x32_bf16(p0, wpf[nt][0], acc, 0,0,0);
                acc = __builtin_amdgcn_mfma_f32_16x16x32_bf16(p1, wpf[nt][1], acc, 0,0,0);
                sacc[nt] = acc;
            }
        }
        __syncthreads();                    // all p-reads complete before overwrite
        #pragma unroll
        for (int nt = 0; nt < 4; ++nt)
            #pragma unroll
            for (int r = 0; r < 4; ++r)
                hS[(4*fg + r)*72 + 16*nt + fr] = f2bf(sacc[nt][r] + bpv[nt]);
        __syncthreads();

        // ---- residual 1 (read own cells), then LN2 in-place ----
        #pragma unroll
        for (int i = 0; i < 4; ++i) {
            uint2 w = *((const uint2*)(hS + xr*72 + xc + 4*i));
            xv[i][0] += bf2f(w.x & 0xffffu); xv[i][1] += bf2f(w.x >> 16);
            xv[i][2] += bf2f(w.y & 0xffffu); xv[i][3] += bf2f(w.y >> 16);
        }
        {
            float s = 0.f, ss = 0.f;
            #pragma unroll
            for (int i = 0; i < 4; ++i)
                #pragma unroll
                for (int j = 0; j < 4; ++j) { float v = xv[i][j]; s += v; ss += v*v; }
            s += __shfl_xor(s, 1, 64); ss += __shfl_xor(ss, 1, 64);
            s += __shfl_xor(s, 2, 64); ss += __shfl_xor(ss, 2, 64);
            float mu  = s * 0.015625f;
            float inv = rsqrtf(ss * 0.015625f - mu*mu + 1e-5f);
            #pragma unroll
            for (int i = 0; i < 4; ++i) {
                uint2 w;
                w.x = (unsigned)f2bf((xv[i][0]-mu)*inv*g2v[4*i+0] + be2v[4*i+0])
                    | ((unsigned)f2bf((xv[i][1]-mu)*inv*g2v[4*i+1] + be2v[4*i+1]) << 16);
                w.y = (unsigned)f2bf((xv[i][2]-mu)*inv*g2v[4*i+2] + be2v[4*i+2])
                    | ((unsigned)f2bf((xv[i][3]-mu)*inv*g2v[4*i+3] + be2v[4*i+3]) << 16);
                *((uint2*)(hS + xr*72 + xc + 4*i)) = w;
            }
        }
        __syncthreads();

        // ---- MLP ----
        bf16x8 c0 = *(const bf16x8*)(hS + fr*72 + 8*fg);
        bf16x8 c1 = *(const bf16x8*)(hS + fr*72 + 8*fg + 32);
        f32x4 ff[4];
        #pragma unroll
        for (int nt = 0; nt < 4; ++nt) { f32x4 z = {0.f,0.f,0.f,0.f}; ff[nt] = z; }
        #pragma unroll
        for (int np = 0; np < 8; ++np) {
            unsigned short* sl = (np & 1) ? sl1 : sl0;
            #pragma unroll
            for (int q = 0; q < 2; ++q) {
                int nt1 = 2*np + q;
                bf16x8 u0 = *(const bf16x8*)(LDS + 24576 + (((nt1*2+0)*64 + lane) << 4));
                bf16x8 u1 = *(const bf16x8*)(LDS + 24576 + (((nt1*2+1)*64 + lane) << 4));
                f32x4 acc = {0.f,0.f,0.f,0.f};
                acc = __builtin_amdgcn_mfma_f32_16x16x32_bf16(c0, u0, acc, 0,0,0);
                acc = __builtin_amdgcn_mfma_f32_16x16x32_bf16(c1, u1, acc, 0,0,0);
                #pragma unroll
                for (int r = 0; r < 4; ++r)
                    sl[(4*fg + r)*40 + 16*q + fr] = f2bf(fmaxf(acc[r] + b1v[nt1], 0.f));
            }
            __syncthreads();
            bf16x8 as = *(const bf16x8*)(sl + fr*40 + 8*fg);
            #pragma unroll
            for (int nt2 = 0; nt2 < 4; ++nt2) {
                bf16x8 wb = *(const bf16x8*)(LDS + 57344 + (((np*4 + nt2)*64 + lane) << 4));
                ff[nt2] = __builtin_amdgcn_mfma_f32_16x16x32_bf16(as, wb, ff[nt2], 0,0,0);
            }
        }
        #pragma unroll
        for (int nt2 = 0; nt2 < 4; ++nt2)
            #pragma unroll
            for (int r = 0; r < 4; ++r)
                hS[(4*fg + r)*72 + 16*nt2 + fr] = f2bf(ff[nt2][r] + b2v[nt2]);
        __syncthreads();

        // ---- residual 2 + store ----
        #pragma unroll
        for (int i = 0; i < 4; ++i) {
            uint2 w = *((const uint2*)(hS + xr*72 + xc + 4*i));
            f32x4 o = xv[i];
            o[0] += bf2f(w.x & 0xffffu); o[1] += bf2f(w.x >> 16);
            o[2] += bf2f(w.y & 0xffffu); o[3] += bf2f(w.y >> 16);
            *((f32x4*)(ob + xr*64 + xc + 4*i)) = o;
        }
        __syncthreads();
    }
}

extern "C" void kernel_launch(void* const* d_in, const int* in_sizes, int n_in,
                              void* d_out, int out_size, void* d_ws, size_t ws_size,
                              hipStream_t stream) {
    const float* x   = (const float*)d_in[0];
    const float* Wq  = (const float*)d_in[1];
    const float* Wk  = (const float*)d_in[2];
    const float* Wv  = (const float*)d_in[3];
    const float* Wp  = (const float*)d_in[4];
    const float* bp  = (const float*)d_in[5];
    const float* W1  = (const float*)d_in[6];
    const float* b1  = (const float*)d_in[7];
    const float* W2  = (const float*)d_in[8];
    const float* b2  = (const float*)d_in[9];
    const float* g1  = (const float*)d_in[10];
    const float* be1 = (const float*)d_in[11];
    const float* g2  = (const float*)d_in[12];
    const float* be2 = (const float*)d_in[13];
    int nPairs = in_sizes[0] / 1024;   // (B*T*C) / (2*8*64) = 32768
    fused_block<<<dim3(256), dim3(512), 0, stream>>>(
        x, Wq, Wk, Wv, Wp, bp, W1, b1, W2, b2, g1, be1, g2, be2,
        (float*)d_out, nPairs);
}